// Round 6
// baseline (640.334 us; speedup 1.0000x reference)
//
#include <hip/hip_runtime.h>
#include <hip/hip_bf16.h>

typedef __attribute__((ext_vector_type(4))) float f32x4;
typedef __attribute__((ext_vector_type(8))) short s16x8;
typedef __attribute__((ext_vector_type(4))) int int4v;

#define DEVI __device__ __forceinline__

constexpr int NN = 50000;
constexpr int NE = 200000;
constexpr float BN_EPS = 1e-5f;

DEVI float bfbits2f(unsigned v) { union { unsigned u; float f; } t; t.u = v << 16; return t.f; }
DEVI float lrelu_f(float v) { return v >= 0.f ? v : 0.01f * v; }

// ---------------- prep: W2T[n][k] = bf16(W2[k][n]) for both layers ----------------
__global__ void k_transpose_w2(const float* __restrict__ A0, const float* __restrict__ A1,
                               __hip_bfloat16* __restrict__ T0, __hip_bfloat16* __restrict__ T1) {
  const float* W2 = blockIdx.y ? A1 : A0;
  __hip_bfloat16* W2T = blockIdx.y ? T1 : T0;
  __shared__ float tile[32][33];
  int bx = blockIdx.x % 16, by = blockIdx.x / 16;
  int t = threadIdx.x;
  int r = t / 32, c = t % 32;
  for (int rr = r; rr < 32; rr += 8)
    tile[rr][c] = W2[(size_t)(by * 32 + rr) * 512 + bx * 32 + c];
  __syncthreads();
  for (int rr = r; rr < 32; rr += 8)
    W2T[(size_t)(bx * 32 + rr) * 512 + by * 32 + c] = __float2bfloat16(tile[c][rr]);
}

// W1T[n][k] = bf16(W1[k][n]); W1 is [8][512]
__global__ void k_transpose_w1(const float* __restrict__ A0, const float* __restrict__ A1,
                               __hip_bfloat16* __restrict__ T0, __hip_bfloat16* __restrict__ T1) {
  const float* W1 = blockIdx.y ? A1 : A0;
  __hip_bfloat16* W1T = blockIdx.y ? T1 : T0;
  int tid = blockIdx.x * 256 + threadIdx.x;
  if (tid < 8 * 512) {
    int k = tid / 512, n = tid % 512;
    W1T[n * 8 + k] = __float2bfloat16(W1[tid]);
  }
}

// ---------------- counting sort by dst -> perm ----------------
__global__ void k_count(const int* __restrict__ dst, int* __restrict__ cnt) {
  int e = blockIdx.x * 256 + threadIdx.x;
  if (e < NE) atomicAdd(&cnt[dst[e]], 1);
}

constexpr int SCAN_ELEMS = 1024;  // per block (256 threads x 4)
__global__ void k_scan1(const int* __restrict__ cnt, int* __restrict__ base, int* __restrict__ aux, int n) {
  __shared__ int sw[256];
  int b = blockIdx.x, t = threadIdx.x;
  int i0 = b * SCAN_ELEMS + t * 4;
  int v[4]; int s = 0;
  #pragma unroll
  for (int j = 0; j < 4; j++) { int idx = i0 + j; v[j] = (idx < n) ? cnt[idx] : 0; s += v[j]; }
  sw[t] = s; __syncthreads();
  for (int d = 1; d < 256; d <<= 1) {
    int val = (t >= d) ? sw[t - d] : 0;
    __syncthreads();
    sw[t] += val;
    __syncthreads();
  }
  int run = (t > 0) ? sw[t - 1] : 0;
  #pragma unroll
  for (int j = 0; j < 4; j++) { int idx = i0 + j; if (idx < n) base[idx] = run; run += v[j]; }
  if (t == 255) aux[b] = sw[255];
}

__global__ void k_scan2(int* aux, int nb) {
  if (threadIdx.x == 0 && blockIdx.x == 0) {
    int run = 0;
    for (int i = 0; i < nb; i++) { int v = aux[i]; aux[i] = run; run += v; }
  }
}

__global__ void k_scan3(int* __restrict__ base, int* __restrict__ cursor, const int* __restrict__ aux, int n) {
  int i = blockIdx.x * 256 + threadIdx.x;
  if (i < n) { int v = base[i] + aux[i / SCAN_ELEMS]; base[i] = v; cursor[i] = v; }
}

__global__ void k_place(const int* __restrict__ dst, int* __restrict__ cursor, int* __restrict__ perm) {
  int e = blockIdx.x * 256 + threadIdx.x;
  if (e < NE) { int p = atomicAdd(&cursor[dst[e]], 1); perm[p] = e; }
}

// ---------------- fused edge kernel v6: single-wave blocks, barrier-free, global-B ----------------
// msg_e = einsum('i,io->o', x[src_e], reshape(lrelu(ea_e@W1+b1)@W2 + b2, [FIN,FOUT]))
// One wave owns 64 edges. All LDS wave-private. B-fragments read directly from
// L2-resident W2T (no shared staging, no __syncthreads in the hot path),
// software-pipelined 2-deep in registers.
template <int FIN, int FOUT>
__global__ __launch_bounds__(64, 2)
void k_edge(const float* __restrict__ x, const float* __restrict__ ea,
            const int* __restrict__ srcI,
            const __hip_bfloat16* __restrict__ W1T, const float* __restrict__ b1,
            const __hip_bfloat16* __restrict__ W2T, const float* __restrict__ b2,
            __hip_bfloat16* __restrict__ msgb)
{
  static_assert(FOUT == 32 || FOUT == 16, "");
  constexpr int TM = 64;           // edges per block (= per wave)
  constexpr int CG = 32;           // cols per group
  constexpr int NCGI = 16;
  constexpr int KH = 256;          // K per sweep
  constexpr int NKC = 4;           // 64-k chunks per sweep
  constexpr int NOT = FOUT / 16;
  constexpr int XLDS = TM + 8;

  __shared__ __align__(16) char gme[64 * 128];              // 8KB g chunk (swizzled)
  __shared__ __align__(16) __hip_bfloat16 eab[TM][8];       // 1KB
  __shared__ __align__(16) __hip_bfloat16 xlt[FIN][XLDS];   // transposed x, bf16

  const int lane = threadIdx.x & 63;
  const int l15 = lane & 15, l4 = lane >> 4;
  const int e0 = blockIdx.x * TM;
  const int rem = min(TM, NE - e0);

  // ---- prologue: one edge per lane ----
  {
    int er = e0 + min(lane, rem - 1);
    float4 v0 = *(const float4*)(ea + (size_t)er * 8);
    float4 v1 = *(const float4*)(ea + (size_t)er * 8 + 4);
    __hip_bfloat16* p = &eab[lane][0];
    p[0] = __float2bfloat16(v0.x); p[1] = __float2bfloat16(v0.y);
    p[2] = __float2bfloat16(v0.z); p[3] = __float2bfloat16(v0.w);
    p[4] = __float2bfloat16(v1.x); p[5] = __float2bfloat16(v1.y);
    p[6] = __float2bfloat16(v1.z); p[7] = __float2bfloat16(v1.w);
    int s = srcI[er];
    #pragma unroll
    for (int q = 0; q < FIN / 4; q++) {
      float4 xv4 = *(const float4*)(x + (size_t)s * FIN + q * 4);
      xlt[q * 4 + 0][lane] = __float2bfloat16(xv4.x);
      xlt[q * 4 + 1][lane] = __float2bfloat16(xv4.y);
      xlt[q * 4 + 2][lane] = __float2bfloat16(xv4.z);
      xlt[q * 4 + 3][lane] = __float2bfloat16(xv4.w);
    }
  }
  __syncthreads();   // single wave: compiles to a cheap waitcnt(+barrier)

  f32x4 msg[4][NOT];
  #pragma unroll
  for (int rt = 0; rt < 4; rt++)
    #pragma unroll
    for (int ot = 0; ot < NOT; ot++) msg[rt][ot] = (f32x4)(0.f);

  s16x8 af[NKC][4][2];   // A fragments: 64 rows x 256 K, pinned resident
  int4v bwreg[2][2];     // 2-deep B pipeline: [stage parity][ks]

  for (int sw = 0; sw < 2; ++sw) {
    // ---- g-phase: g = lrelu(ea@W1+b1), 64 rows x K-half, via wave-private LDS chunk ----
    s16x8 afe[4];
    #pragma unroll
    for (int rt = 0; rt < 4; rt++) {
      s16x8 tv = *(const s16x8*)(&eab[rt * 16 + l15][0]);
      afe[rt] = (lane < 16) ? tv : (s16x8)0;
    }
    #pragma unroll
    for (int kc = 0; kc < NKC; kc++) {
      #pragma unroll
      for (int ct = 0; ct < 4; ct++) {
        int c = sw * KH + kc * 64 + ct * 16 + l15;
        s16x8 bw = *(const s16x8*)(W1T + c * 8);
        bw = (lane < 16) ? bw : (s16x8)0;
        float b1v = b1[c];
        #pragma unroll
        for (int rt = 0; rt < 4; rt++) {
          f32x4 d = __builtin_amdgcn_mfma_f32_16x16x32_bf16(afe[rt], bw, (f32x4)(0.f), 0, 0, 0);
          #pragma unroll
          for (int r = 0; r < 4; r++) {
            int rloc = rt * 16 + l4 * 4 + r;
            float gv = d[r] + b1v;
            gv = gv >= 0.f ? gv : 0.01f * gv;
            int byt = (rloc * 128 + (ct * 16 + l15) * 2) ^ (((rloc + (rloc >> 2)) & 3) << 5);
            *(__hip_bfloat16*)(gme + byt) = __float2bfloat16(gv);
          }
        }
      }
      #pragma unroll
      for (int rt = 0; rt < 4; rt++)
        #pragma unroll
        for (int ks = 0; ks < 2; ks++) {
          int rloc = rt * 16 + l15;
          int byt = (rloc * 128 + (ks * 32 + l4 * 8) * 2) ^ (((rloc + (rloc >> 2)) & 3) << 5);
          af[kc][rt][ks] = *(const s16x8*)(gme + byt);
        }
    }
    // pin A fragments (forbid remat-from-LDS)
    #pragma unroll
    for (int kc = 0; kc < NKC; kc++)
      #pragma unroll
      for (int rt = 0; rt < 4; rt++)
        #pragma unroll
        for (int ks = 0; ks < 2; ks++)
          asm volatile("" : "+v"(af[kc][rt][ks]));

    // ---- main loop: B direct from global (L2), stages of {2 loads, 8 MFMA} ----
    const char* Wbase = (const char*)W2T + (size_t)sw * KH * 2;
    auto loadB = [&](int cgi2, int stg, int4v* dst) {
      const int ct = stg & 1, kc = stg >> 1;
      #pragma unroll
      for (int ks = 0; ks < 2; ks++) {
        int col = cgi2 * CG + ct * 16 + l15;
        int koff = kc * 64 + ks * 32 + l4 * 8;
        dst[ks] = *(const int4v*)(Wbase + (size_t)col * 1024 + koff * 2);
      }
    };

    loadB(0, 0, bwreg[0]);
    for (int cgi = 0; cgi < NCGI; ++cgi) {
      f32x4 acc[4][2];
      #pragma unroll
      for (int rt = 0; rt < 4; rt++) { acc[rt][0] = (f32x4)(0.f); acc[rt][1] = (f32x4)(0.f); }

      #pragma unroll
      for (int s = 0; s < 8; ++s) {
        if (s < 7) loadB(cgi, s + 1, bwreg[(s + 1) & 1]);
        else if (cgi + 1 < NCGI) loadB(cgi + 1, 0, bwreg[0]);
        const int ct = s & 1, kc = s >> 1;
        #pragma unroll
        for (int ks = 0; ks < 2; ks++)
          #pragma unroll
          for (int rt = 0; rt < 4; rt++)
            acc[rt][ct] = __builtin_amdgcn_mfma_f32_16x16x32_bf16(af[kc][rt][ks], bwreg[s & 1][ks], acc[rt][ct], 0, 0, 0);
      }

      // epilogue: +b2 (sweep 0 only), scale by x[e, i(col)], fold into msg
      #pragma unroll
      for (int ct = 0; ct < 2; ct++) {
        float b2v = (sw == 0) ? b2[cgi * CG + ct * 16 + l15] : 0.f;
        const int iv = (FOUT == 32) ? cgi : (cgi * 2 + ct);
        const int ot = (FOUT == 32) ? ct : 0;
        #pragma unroll
        for (int rt = 0; rt < 4; rt++) {
          int rbase = rt * 16 + l4 * 4;
          ushort4 xv = *(const ushort4*)(&xlt[iv][rbase]);
          msg[rt][ot][0] += bfbits2f(xv.x) * (acc[rt][ct][0] + b2v);
          msg[rt][ot][1] += bfbits2f(xv.y) * (acc[rt][ct][1] + b2v);
          msg[rt][ot][2] += bfbits2f(xv.z) * (acc[rt][ct][2] + b2v);
          msg[rt][ot][3] += bfbits2f(xv.w) * (acc[rt][ct][3] + b2v);
        }
      }
    }
  }

  // ---- dense coalesced bf16 store ----
  #pragma unroll
  for (int rt = 0; rt < 4; rt++)
    #pragma unroll
    for (int r = 0; r < 4; r++) {
      int row = rt * 16 + l4 * 4 + r;
      if (row < rem) {
        #pragma unroll
        for (int ot = 0; ot < NOT; ot++)
          msgb[(size_t)(e0 + row) * FOUT + ot * 16 + l15] = __float2bfloat16(msg[rt][ot][r]);
      }
    }
}

// ---------------- fused gather + root + bias: h = mean(msg@dst) + x@root + bias ----------------
template <int FIN, int FOUT>
__global__ void k_node_agg(const __hip_bfloat16* __restrict__ msgb, const int* __restrict__ perm,
                           const int* __restrict__ base,
                           const float* __restrict__ x,
                           const float* __restrict__ root,   // [FIN][FOUT]
                           const float* __restrict__ bias,
                           float* __restrict__ h)
{
  __shared__ float rl[FIN * FOUT];
  constexpr int NPB = 256 / FOUT;
  int t = threadIdx.x;
  for (int i = t; i < FIN * FOUT; i += 256) rl[i] = root[i];
  __syncthreads();
  int n = blockIdx.x * NPB + t / FOUT;
  int o = t % FOUT;
  if (n >= NN) return;
  int s = base[n];
  int e = (n + 1 < NN) ? base[n + 1] : NE;
  float sum = 0.f;
  for (int j = s; j < e; j++)
    sum += __bfloat162float(msgb[(size_t)perm[j] * FOUT + o]);
  float acc = sum / fmaxf((float)(e - s), 1.f) + bias[o];
  #pragma unroll
  for (int i = 0; i < FIN; i++)
    acc += x[(size_t)n * FIN + i] * rl[i * FOUT + o];
  h[(size_t)n * FOUT + o] = acc;
}

// ---------------- BN stats: per-column sum & sumsq ----------------
template <int FOUT>
__global__ void k_stats(const float* __restrict__ h, float* __restrict__ ssum, float* __restrict__ ssq) {
  constexpr int RPB = 256 / FOUT;
  int t = threadIdx.x;
  int o = t % FOUT, rr = t / FOUT;
  float v = 0.f, v2 = 0.f;
  for (int r = blockIdx.x * RPB + rr; r < NN; r += gridDim.x * RPB) {
    float y = h[(size_t)r * FOUT + o];
    v += y; v2 += y * y;
  }
  #pragma unroll
  for (int d = FOUT; d < 64; d <<= 1) { v += __shfl_xor(v, d); v2 += __shfl_xor(v2, d); }
  __shared__ float sv[4][32], sq[4][32];
  int wv = t >> 6, ln = t & 63;
  if (ln < FOUT) { sv[wv][ln] = v; sq[wv][ln] = v2; }
  __syncthreads();
  if (t < FOUT) {
    float a = 0.f, b = 0.f;
    #pragma unroll
    for (int w2 = 0; w2 < 4; w2++) { a += sv[w2][t]; b += sq[w2][t]; }
    atomicAdd(&ssum[t], a);
    atomicAdd(&ssq[t], b);
  }
}

// ---------------- BN apply (+optional lrelu) ----------------
template <int FOUT, bool LRELU>
__global__ void k_bn(const float* __restrict__ h, const float* __restrict__ ssum,
                     const float* __restrict__ ssq, const float* __restrict__ gamma,
                     const float* __restrict__ beta, float* __restrict__ out)
{
  int idx = blockIdx.x * 256 + threadIdx.x;
  if (idx * 4 >= NN * FOUT) return;
  float4 v = *(const float4*)(h + (size_t)idx * 4);
  float r[4] = {v.x, v.y, v.z, v.w};
  #pragma unroll
  for (int j = 0; j < 4; j++) {
    int o = (idx * 4 + j) % FOUT;
    float mu = ssum[o] * (1.f / NN);
    float var = ssq[o] * (1.f / NN) - mu * mu;
    float sc = rsqrtf(var + BN_EPS) * gamma[o];
    float y = (r[j] - mu) * sc + beta[o];
    if (LRELU) y = lrelu_f(y);
    r[j] = y;
  }
  *(float4*)(out + (size_t)idx * 4) = make_float4(r[0], r[1], r[2], r[3]);
}

extern "C" void kernel_launch(void* const* d_in, const int* in_sizes, int n_in,
                              void* d_out, int out_size, void* d_ws, size_t ws_size,
                              hipStream_t stream)
{
  const float* x0    = (const float*)d_in[0];
  const float* ea    = (const float*)d_in[1];
  const int*   ei    = (const int*)d_in[2];
  const float* W1_0  = (const float*)d_in[3];
  const float* b1_0  = (const float*)d_in[4];
  const float* W2_0  = (const float*)d_in[5];
  const float* b2_0  = (const float*)d_in[6];
  const float* root0 = (const float*)d_in[7];
  const float* bias0 = (const float*)d_in[8];
  const float* gam0  = (const float*)d_in[9];
  const float* bet0  = (const float*)d_in[10];
  const float* W1_1  = (const float*)d_in[11];
  const float* b1_1  = (const float*)d_in[12];
  const float* W2_1  = (const float*)d_in[13];
  const float* b2_1  = (const float*)d_in[14];
  const float* root1 = (const float*)d_in[15];
  const float* bias1 = (const float*)d_in[16];
  const float* gam1  = (const float*)d_in[17];
  const float* bet1  = (const float*)d_in[18];
  const int* srcI = ei;
  const int* dstI = ei + NE;

  char* ws = (char*)d_ws;
  size_t off = 0;
  auto alloc = [&](size_t bytes) { char* p = ws + off; off += (bytes + 255) & ~(size_t)255; return p; };
  // ---- zeroed region ----
  int*   cnt   = (int*)alloc(50048 * 4);
  float* ssum0 = (float*)alloc(32 * 4);
  float* ssq0  = (float*)alloc(32 * 4);
  float* ssum1 = (float*)alloc(16 * 4);
  float* ssq1  = (float*)alloc(16 * 4);
  size_t zero_bytes = off;
  // ---- rest ----
  int*   base   = (int*)alloc(50048 * 4);
  int*   cursor = (int*)alloc(50048 * 4);
  int*   aux    = (int*)alloc(64 * 4);
  int*   perm   = (int*)alloc((size_t)NE * 4);
  __hip_bfloat16* msgb = (__hip_bfloat16*)alloc((size_t)NE * 32 * 2);  // reused for layer1 (16)
  float* h0 = (float*)alloc((size_t)NN * 32 * 4);
  float* h1 = (float*)alloc((size_t)NN * 16 * 4);
  float* x1 = (float*)alloc((size_t)NN * 32 * 4);
  __hip_bfloat16* W2T0 = (__hip_bfloat16*)alloc(512 * 512 * 2);
  __hip_bfloat16* W2T1 = (__hip_bfloat16*)alloc(512 * 512 * 2);
  __hip_bfloat16* W1T0 = (__hip_bfloat16*)alloc(512 * 8 * 2);
  __hip_bfloat16* W1T1 = (__hip_bfloat16*)alloc(512 * 8 * 2);

  hipMemsetAsync(d_ws, 0, zero_bytes, stream);

  // weight prep (merged across layers)
  k_transpose_w2<<<dim3(256, 2), 256, 0, stream>>>(W2_0, W2_1, W2T0, W2T1);
  k_transpose_w1<<<dim3(16, 2), 256, 0, stream>>>(W1_0, W1_1, W1T0, W1T1);

  // counting sort by dst (shared by both layers)
  constexpr int NSB = (NN + SCAN_ELEMS - 1) / SCAN_ELEMS;  // 49
  k_count<<<(NE + 255) / 256, 256, 0, stream>>>(dstI, cnt);
  k_scan1<<<NSB, 256, 0, stream>>>(cnt, base, aux, NN);
  k_scan2<<<1, 64, 0, stream>>>(aux, NSB);
  k_scan3<<<(NN + 255) / 256, 256, 0, stream>>>(base, cursor, aux, NN);
  k_place<<<(NE + 255) / 256, 256, 0, stream>>>(dstI, cursor, perm);

  constexpr int TM = 64;
  // layer 0
  k_edge<16, 32><<<(NE + TM - 1) / TM, 64, 0, stream>>>(x0, ea, srcI, W1T0, b1_0, W2T0, b2_0, msgb);
  k_node_agg<16, 32><<<(NN + 7) / 8, 256, 0, stream>>>(msgb, perm, base, x0, root0, bias0, h0);
  k_stats<32><<<128, 256, 0, stream>>>(h0, ssum0, ssq0);
  k_bn<32, true><<<((NN * 32 / 4) + 255) / 256, 256, 0, stream>>>(h0, ssum0, ssq0, gam0, bet0, x1);

  // layer 1
  k_edge<32, 16><<<(NE + TM - 1) / TM, 64, 0, stream>>>(x1, ea, srcI, W1T1, b1_1, W2T1, b2_1, msgb);
  k_node_agg<32, 16><<<(NN + 15) / 16, 256, 0, stream>>>(msgb, perm, base, x1, root1, bias1, h1);
  k_stats<16><<<128, 256, 0, stream>>>(h1, ssum1, ssq1);
  k_bn<16, false><<<((NN * 16 / 4) + 255) / 256, 256, 0, stream>>>(h1, ssum1, ssq1, gam1, bet1, (float*)d_out);
}

// Round 7
// 389.630 us; speedup vs baseline: 1.6434x; 1.6434x over previous
//
#include <hip/hip_runtime.h>
#include <hip/hip_bf16.h>

typedef __attribute__((ext_vector_type(4))) float f32x4;
typedef __attribute__((ext_vector_type(8))) short s16x8;
typedef __attribute__((ext_vector_type(4))) int int4v;

#define DEVI __device__ __forceinline__

constexpr int NN = 50000;
constexpr int NE = 200000;
constexpr float BN_EPS = 1e-5f;

DEVI float bfbits2f(unsigned v) { union { unsigned u; float f; } t; t.u = v << 16; return t.f; }
DEVI float lrelu_f(float v) { return v >= 0.f ? v : 0.01f * v; }

// ---------------- prep: W2T[n][k] = bf16(W2[k][n]) for both layers ----------------
__global__ void k_transpose_w2(const float* __restrict__ A0, const float* __restrict__ A1,
                               __hip_bfloat16* __restrict__ T0, __hip_bfloat16* __restrict__ T1) {
  const float* W2 = blockIdx.y ? A1 : A0;
  __hip_bfloat16* W2T = blockIdx.y ? T1 : T0;
  __shared__ float tile[32][33];
  int bx = blockIdx.x % 16, by = blockIdx.x / 16;
  int t = threadIdx.x;
  int r = t / 32, c = t % 32;
  for (int rr = r; rr < 32; rr += 8)
    tile[rr][c] = W2[(size_t)(by * 32 + rr) * 512 + bx * 32 + c];
  __syncthreads();
  for (int rr = r; rr < 32; rr += 8)
    W2T[(size_t)(bx * 32 + rr) * 512 + by * 32 + c] = __float2bfloat16(tile[c][rr]);
}

// W1T[n][k] = bf16(W1[k][n]); W1 is [8][512]
__global__ void k_transpose_w1(const float* __restrict__ A0, const float* __restrict__ A1,
                               __hip_bfloat16* __restrict__ T0, __hip_bfloat16* __restrict__ T1) {
  const float* W1 = blockIdx.y ? A1 : A0;
  __hip_bfloat16* W1T = blockIdx.y ? T1 : T0;
  int tid = blockIdx.x * 256 + threadIdx.x;
  if (tid < 8 * 512) {
    int k = tid / 512, n = tid % 512;
    W1T[n * 8 + k] = __float2bfloat16(W1[tid]);
  }
}

// ---------------- counting sort by dst -> perm ----------------
__global__ void k_count(const int* __restrict__ dst, int* __restrict__ cnt) {
  int e = blockIdx.x * 256 + threadIdx.x;
  if (e < NE) atomicAdd(&cnt[dst[e]], 1);
}

constexpr int SCAN_ELEMS = 1024;  // per block (256 threads x 4)
__global__ void k_scan1(const int* __restrict__ cnt, int* __restrict__ base, int* __restrict__ aux, int n) {
  __shared__ int sw[256];
  int b = blockIdx.x, t = threadIdx.x;
  int i0 = b * SCAN_ELEMS + t * 4;
  int v[4]; int s = 0;
  #pragma unroll
  for (int j = 0; j < 4; j++) { int idx = i0 + j; v[j] = (idx < n) ? cnt[idx] : 0; s += v[j]; }
  sw[t] = s; __syncthreads();
  for (int d = 1; d < 256; d <<= 1) {
    int val = (t >= d) ? sw[t - d] : 0;
    __syncthreads();
    sw[t] += val;
    __syncthreads();
  }
  int run = (t > 0) ? sw[t - 1] : 0;
  #pragma unroll
  for (int j = 0; j < 4; j++) { int idx = i0 + j; if (idx < n) base[idx] = run; run += v[j]; }
  if (t == 255) aux[b] = sw[255];
}

__global__ void k_scan2(int* aux, int nb) {
  if (threadIdx.x == 0 && blockIdx.x == 0) {
    int run = 0;
    for (int i = 0; i < nb; i++) { int v = aux[i]; aux[i] = run; run += v; }
  }
}

__global__ void k_scan3(int* __restrict__ base, int* __restrict__ cursor, const int* __restrict__ aux, int n) {
  int i = blockIdx.x * 256 + threadIdx.x;
  if (i < n) { int v = base[i] + aux[i / SCAN_ELEMS]; base[i] = v; cursor[i] = v; }
}

__global__ void k_place(const int* __restrict__ dst, int* __restrict__ cursor, int* __restrict__ perm) {
  int e = blockIdx.x * 256 + threadIdx.x;
  if (e < NE) { int p = atomicAdd(&cursor[dst[e]], 1); perm[p] = e; }
}

// ---------------- fused edge kernel v7: R5 core + LDS diet for 2-3 blocks/CU ----------------
// msg_e = einsum('i,io->o', x[src_e], reshape(lrelu(ea_e@W1+b1)@W2 + b2, [FIN,FOUT]))
template <int FIN, int FOUT>
__global__ __launch_bounds__(512, 2)
void k_edge(const float* __restrict__ x, const float* __restrict__ ea,
            const int* __restrict__ srcI,
            const __hip_bfloat16* __restrict__ W1T, const float* __restrict__ b1,
            const __hip_bfloat16* __restrict__ W2T, const float* __restrict__ b2,
            __hip_bfloat16* __restrict__ msgb)
{
  static_assert(FOUT == 32 || FOUT == 16, "");
  constexpr int TM = 512;          // rows per block (8 waves x 64)
  constexpr int CG = 32;           // cols per staged group
  constexpr int NCGI = 16;
  constexpr int KH = 256;          // K per sweep
  constexpr int NKC = 4;           // 64-k chunks per sweep
  constexpr int NOT = FOUT / 16;
  constexpr int BSTRIDE = KH * 2 + 16;   // 528 B
  constexpr int XLDS = TM + 8;

  // union: g-phase = 8 waves x 4KB private chunks (32KB); cgi loop = double bbuf (33.8KB)
  __shared__ __align__(16) char ubuf[2 * CG * BSTRIDE];     // 33792 B
  __shared__ __align__(16) __hip_bfloat16 xlt[FIN][XLDS];   // transposed x, bf16

  const int tid = threadIdx.x;
  const int lane = tid & 63, w = tid >> 6;
  const int l15 = lane & 15, l4 = lane >> 4;
  const int e0 = blockIdx.x * TM;
  const int rem = min(TM, NE - e0);
  const int wrow0 = w * 64;

  // ---- prologue: one row per thread (wave-private rows -> no barrier needed) ----
  s16x8 afe[4];   // hoisted A-fragments of ea (held in regs for both sweeps)
  {
    int er = e0 + min(tid, rem - 1);
    float4 v0 = *(const float4*)(ea + (size_t)er * 8);
    float4 v1 = *(const float4*)(ea + (size_t)er * 8 + 4);
    union { s16x8 v; int i4[4]; } earow;
    __hip_bfloat16* p = (__hip_bfloat16*)&earow;
    p[0] = __float2bfloat16(v0.x); p[1] = __float2bfloat16(v0.y);
    p[2] = __float2bfloat16(v0.z); p[3] = __float2bfloat16(v0.w);
    p[4] = __float2bfloat16(v1.x); p[5] = __float2bfloat16(v1.y);
    p[6] = __float2bfloat16(v1.z); p[7] = __float2bfloat16(v1.w);
    #pragma unroll
    for (int rt = 0; rt < 4; rt++) {
      union { s16x8 v; int i4[4]; } t2;
      #pragma unroll
      for (int q = 0; q < 4; q++) t2.i4[q] = __shfl(earow.i4[q], rt * 16 + l15);
      afe[rt] = (lane < 16) ? t2.v : (s16x8)0;
    }
    int s = srcI[er];
    #pragma unroll
    for (int q = 0; q < FIN / 4; q++) {
      float4 xv4 = *(const float4*)(x + (size_t)s * FIN + q * 4);
      xlt[q * 4 + 0][tid] = __float2bfloat16(xv4.x);
      xlt[q * 4 + 1][tid] = __float2bfloat16(xv4.y);
      xlt[q * 4 + 2][tid] = __float2bfloat16(xv4.z);
      xlt[q * 4 + 3][tid] = __float2bfloat16(xv4.w);
    }
  }

  f32x4 msg[4][NOT];
  #pragma unroll
  for (int rt = 0; rt < 4; rt++)
    #pragma unroll
    for (int ot = 0; ot < NOT; ot++) msg[rt][ot] = (f32x4)(0.f);

  s16x8 af[NKC][4][2];   // A fragments: 64 rows x 256 K, resident (AGPR/VGPR)
  int4v sr0, sr1;

  for (int sw = 0; sw < 2; ++sw) {
    // issue first W2T stage load early (latency hides under g-phase)
    {
      int n = tid >> 4, s0 = tid & 15;
      const char* gp = (const char*)(W2T + (size_t)n * 512 + sw * KH);
      sr0 = *(const int4v*)(gp + s0 * 16);
      sr1 = *(const int4v*)(gp + (s0 + 16) * 16);
    }
    // ---- g-phase: two 32-row halves through a wave-private 4KB LDS chunk ----
    char* gme = ubuf + w * 4096;
    #pragma unroll
    for (int h = 0; h < 2; ++h) {
      #pragma unroll
      for (int kc = 0; kc < NKC; kc++) {
        #pragma unroll
        for (int ct = 0; ct < 4; ct++) {
          int c = sw * KH + kc * 64 + ct * 16 + l15;
          s16x8 bw = *(const s16x8*)(W1T + c * 8);
          bw = (lane < 16) ? bw : (s16x8)0;
          float b1v = b1[c];
          #pragma unroll
          for (int rt2 = 0; rt2 < 2; rt2++) {
            f32x4 d = __builtin_amdgcn_mfma_f32_16x16x32_bf16(afe[h * 2 + rt2], bw, (f32x4)(0.f), 0, 0, 0);
            #pragma unroll
            for (int r = 0; r < 4; r++) {
              int rloc = rt2 * 16 + l4 * 4 + r;
              float gv = d[r] + b1v;
              gv = gv >= 0.f ? gv : 0.01f * gv;
              int byt = (rloc * 128 + (ct * 16 + l15) * 2) ^ (((rloc + (rloc >> 2)) & 3) << 5);
              *(__hip_bfloat16*)(gme + byt) = __float2bfloat16(gv);
            }
          }
        }
        #pragma unroll
        for (int rt2 = 0; rt2 < 2; rt2++)
          #pragma unroll
          for (int ks = 0; ks < 2; ks++) {
            int rloc = rt2 * 16 + l15;
            int byt = (rloc * 128 + (ks * 32 + l4 * 8) * 2) ^ (((rloc + (rloc >> 2)) & 3) << 5);
            af[kc][h * 2 + rt2][ks] = *(const s16x8*)(gme + byt);
          }
      }
    }
    // pin A fragments in regs -- forbids remat-from-LDS sinking
    #pragma unroll
    for (int kc = 0; kc < NKC; kc++)
      #pragma unroll
      for (int rt = 0; rt < 4; rt++)
        #pragma unroll
        for (int ks = 0; ks < 2; ks++)
          asm volatile("" : "+v"(af[kc][rt][ks]));
    __syncthreads();               // all g reads done; ubuf becomes bbuf
    {
      int n = tid >> 4, s0 = tid & 15;
      *(int4v*)(ubuf + n * BSTRIDE + s0 * 16) = sr0;
      *(int4v*)(ubuf + n * BSTRIDE + (s0 + 16) * 16) = sr1;
    }
    __syncthreads();

    for (int cgi = 0; cgi < NCGI; ++cgi) {
      if (cgi + 1 < NCGI) {   // prefetch next col-group to regs
        int n = tid >> 4, s0 = tid & 15;
        const char* gp = (const char*)(W2T + (size_t)((cgi + 1) * CG + n) * 512 + sw * KH);
        sr0 = *(const int4v*)(gp + s0 * 16);
        sr1 = *(const int4v*)(gp + (s0 + 16) * 16);
      }
      const char* bb = ubuf + (cgi & 1) * (CG * BSTRIDE);
      f32x4 acc[4][2];
      #pragma unroll
      for (int rt = 0; rt < 4; rt++) { acc[rt][0] = (f32x4)(0.f); acc[rt][1] = (f32x4)(0.f); }

      #pragma unroll
      for (int kc = 0; kc < NKC; kc++)
        #pragma unroll
        for (int ct = 0; ct < 2; ct++) {
          int c = ct * 16 + l15;
          #pragma unroll
          for (int ks = 0; ks < 2; ks++) {
            const s16x8 bw = *(const s16x8*)(bb + c * BSTRIDE + kc * 128 + ks * 64 + l4 * 16);
            #pragma unroll
            for (int rt = 0; rt < 4; rt++)
              acc[rt][ct] = __builtin_amdgcn_mfma_f32_16x16x32_bf16(af[kc][rt][ks], bw, acc[rt][ct], 0, 0, 0);
          }
        }

      // epilogue: +b2 (sweep 0 only), scale by x[e, i(col)], fold into msg
      #pragma unroll
      for (int ct = 0; ct < 2; ct++) {
        float b2v = (sw == 0) ? b2[cgi * CG + ct * 16 + l15] : 0.f;
        const int iv = (FOUT == 32) ? cgi : (cgi * 2 + ct);
        const int ot = (FOUT == 32) ? ct : 0;
        #pragma unroll
        for (int rt = 0; rt < 4; rt++) {
          int rbase = wrow0 + rt * 16 + l4 * 4;
          ushort4 xv = *(const ushort4*)(&xlt[iv][rbase]);
          msg[rt][ot][0] += bfbits2f(xv.x) * (acc[rt][ct][0] + b2v);
          msg[rt][ot][1] += bfbits2f(xv.y) * (acc[rt][ct][1] + b2v);
          msg[rt][ot][2] += bfbits2f(xv.z) * (acc[rt][ct][2] + b2v);
          msg[rt][ot][3] += bfbits2f(xv.w) * (acc[rt][ct][3] + b2v);
        }
      }
      if (cgi + 1 < NCGI) {   // write prefetched group to the other buffer
        int n = tid >> 4, s0 = tid & 15;
        char* bw2 = ubuf + ((cgi + 1) & 1) * (CG * BSTRIDE);
        *(int4v*)(bw2 + n * BSTRIDE + s0 * 16) = sr0;
        *(int4v*)(bw2 + n * BSTRIDE + (s0 + 16) * 16) = sr1;
      }
      __syncthreads();
    }
  }

  // ---- dense coalesced bf16 store ----
  #pragma unroll
  for (int rt = 0; rt < 4; rt++)
    #pragma unroll
    for (int r = 0; r < 4; r++) {
      int row = wrow0 + rt * 16 + l4 * 4 + r;
      if (row < rem) {
        #pragma unroll
        for (int ot = 0; ot < NOT; ot++)
          msgb[(size_t)(e0 + row) * FOUT + ot * 16 + l15] = __float2bfloat16(msg[rt][ot][r]);
      }
    }
}

// ---------------- fused gather + root + bias: h = mean(msg@dst) + x@root + bias ----------------
template <int FIN, int FOUT>
__global__ void k_node_agg(const __hip_bfloat16* __restrict__ msgb, const int* __restrict__ perm,
                           const int* __restrict__ base,
                           const float* __restrict__ x,
                           const float* __restrict__ root,   // [FIN][FOUT]
                           const float* __restrict__ bias,
                           float* __restrict__ h)
{
  __shared__ float rl[FIN * FOUT];
  constexpr int NPB = 256 / FOUT;
  int t = threadIdx.x;
  for (int i = t; i < FIN * FOUT; i += 256) rl[i] = root[i];
  __syncthreads();
  int n = blockIdx.x * NPB + t / FOUT;
  int o = t % FOUT;
  if (n >= NN) return;
  int s = base[n];
  int e = (n + 1 < NN) ? base[n + 1] : NE;
  float sum = 0.f;
  for (int j = s; j < e; j++)
    sum += __bfloat162float(msgb[(size_t)perm[j] * FOUT + o]);
  float acc = sum / fmaxf((float)(e - s), 1.f) + bias[o];
  #pragma unroll
  for (int i = 0; i < FIN; i++)
    acc += x[(size_t)n * FIN + i] * rl[i * FOUT + o];
  h[(size_t)n * FOUT + o] = acc;
}

// ---------------- BN stats: per-column sum & sumsq ----------------
template <int FOUT>
__global__ void k_stats(const float* __restrict__ h, float* __restrict__ ssum, float* __restrict__ ssq) {
  constexpr int RPB = 256 / FOUT;
  int t = threadIdx.x;
  int o = t % FOUT, rr = t / FOUT;
  float v = 0.f, v2 = 0.f;
  for (int r = blockIdx.x * RPB + rr; r < NN; r += gridDim.x * RPB) {
    float y = h[(size_t)r * FOUT + o];
    v += y; v2 += y * y;
  }
  #pragma unroll
  for (int d = FOUT; d < 64; d <<= 1) { v += __shfl_xor(v, d); v2 += __shfl_xor(v2, d); }
  __shared__ float sv[4][32], sq[4][32];
  int wv = t >> 6, ln = t & 63;
  if (ln < FOUT) { sv[wv][ln] = v; sq[wv][ln] = v2; }
  __syncthreads();
  if (t < FOUT) {
    float a = 0.f, b = 0.f;
    #pragma unroll
    for (int w2 = 0; w2 < 4; w2++) { a += sv[w2][t]; b += sq[w2][t]; }
    atomicAdd(&ssum[t], a);
    atomicAdd(&ssq[t], b);
  }
}

// ---------------- BN apply (+optional lrelu) ----------------
template <int FOUT, bool LRELU>
__global__ void k_bn(const float* __restrict__ h, const float* __restrict__ ssum,
                     const float* __restrict__ ssq, const float* __restrict__ gamma,
                     const float* __restrict__ beta, float* __restrict__ out)
{
  int idx = blockIdx.x * 256 + threadIdx.x;
  if (idx * 4 >= NN * FOUT) return;
  float4 v = *(const float4*)(h + (size_t)idx * 4);
  float r[4] = {v.x, v.y, v.z, v.w};
  #pragma unroll
  for (int j = 0; j < 4; j++) {
    int o = (idx * 4 + j) % FOUT;
    float mu = ssum[o] * (1.f / NN);
    float var = ssq[o] * (1.f / NN) - mu * mu;
    float sc = rsqrtf(var + BN_EPS) * gamma[o];
    float y = (r[j] - mu) * sc + beta[o];
    if (LRELU) y = lrelu_f(y);
    r[j] = y;
  }
  *(float4*)(out + (size_t)idx * 4) = make_float4(r[0], r[1], r[2], r[3]);
}

extern "C" void kernel_launch(void* const* d_in, const int* in_sizes, int n_in,
                              void* d_out, int out_size, void* d_ws, size_t ws_size,
                              hipStream_t stream)
{
  const float* x0    = (const float*)d_in[0];
  const float* ea    = (const float*)d_in[1];
  const int*   ei    = (const int*)d_in[2];
  const float* W1_0  = (const float*)d_in[3];
  const float* b1_0  = (const float*)d_in[4];
  const float* W2_0  = (const float*)d_in[5];
  const float* b2_0  = (const float*)d_in[6];
  const float* root0 = (const float*)d_in[7];
  const float* bias0 = (const float*)d_in[8];
  const float* gam0  = (const float*)d_in[9];
  const float* bet0  = (const float*)d_in[10];
  const float* W1_1  = (const float*)d_in[11];
  const float* b1_1  = (const float*)d_in[12];
  const float* W2_1  = (const float*)d_in[13];
  const float* b2_1  = (const float*)d_in[14];
  const float* root1 = (const float*)d_in[15];
  const float* bias1 = (const float*)d_in[16];
  const float* gam1  = (const float*)d_in[17];
  const float* bet1  = (const float*)d_in[18];
  const int* srcI = ei;
  const int* dstI = ei + NE;

  char* ws = (char*)d_ws;
  size_t off = 0;
  auto alloc = [&](size_t bytes) { char* p = ws + off; off += (bytes + 255) & ~(size_t)255; return p; };
  // ---- zeroed region ----
  int*   cnt   = (int*)alloc(50048 * 4);
  float* ssum0 = (float*)alloc(32 * 4);
  float* ssq0  = (float*)alloc(32 * 4);
  float* ssum1 = (float*)alloc(16 * 4);
  float* ssq1  = (float*)alloc(16 * 4);
  size_t zero_bytes = off;
  // ---- rest ----
  int*   base   = (int*)alloc(50048 * 4);
  int*   cursor = (int*)alloc(50048 * 4);
  int*   aux    = (int*)alloc(64 * 4);
  int*   perm   = (int*)alloc((size_t)NE * 4);
  __hip_bfloat16* msgb = (__hip_bfloat16*)alloc((size_t)NE * 32 * 2);  // reused for layer1 (16)
  float* h0 = (float*)alloc((size_t)NN * 32 * 4);
  float* h1 = (float*)alloc((size_t)NN * 16 * 4);
  float* x1 = (float*)alloc((size_t)NN * 32 * 4);
  __hip_bfloat16* W2T0 = (__hip_bfloat16*)alloc(512 * 512 * 2);
  __hip_bfloat16* W2T1 = (__hip_bfloat16*)alloc(512 * 512 * 2);
  __hip_bfloat16* W1T0 = (__hip_bfloat16*)alloc(512 * 8 * 2);
  __hip_bfloat16* W1T1 = (__hip_bfloat16*)alloc(512 * 8 * 2);

  hipMemsetAsync(d_ws, 0, zero_bytes, stream);

  // weight prep (merged across layers)
  k_transpose_w2<<<dim3(256, 2), 256, 0, stream>>>(W2_0, W2_1, W2T0, W2T1);
  k_transpose_w1<<<dim3(16, 2), 256, 0, stream>>>(W1_0, W1_1, W1T0, W1T1);

  // counting sort by dst (shared by both layers)
  constexpr int NSB = (NN + SCAN_ELEMS - 1) / SCAN_ELEMS;  // 49
  k_count<<<(NE + 255) / 256, 256, 0, stream>>>(dstI, cnt);
  k_scan1<<<NSB, 256, 0, stream>>>(cnt, base, aux, NN);
  k_scan2<<<1, 64, 0, stream>>>(aux, NSB);
  k_scan3<<<(NN + 255) / 256, 256, 0, stream>>>(base, cursor, aux, NN);
  k_place<<<(NE + 255) / 256, 256, 0, stream>>>(dstI, cursor, perm);

  constexpr int TM = 512;
  // layer 0
  k_edge<16, 32><<<(NE + TM - 1) / TM, 512, 0, stream>>>(x0, ea, srcI, W1T0, b1_0, W2T0, b2_0, msgb);
  k_node_agg<16, 32><<<(NN + 7) / 8, 256, 0, stream>>>(msgb, perm, base, x0, root0, bias0, h0);
  k_stats<32><<<128, 256, 0, stream>>>(h0, ssum0, ssq0);
  k_bn<32, true><<<((NN * 32 / 4) + 255) / 256, 256, 0, stream>>>(h0, ssum0, ssq0, gam0, bet0, x1);

  // layer 1
  k_edge<32, 16><<<(NE + TM - 1) / TM, 512, 0, stream>>>(x1, ea, srcI, W1T1, b1_1, W2T1, b2_1, msgb);
  k_node_agg<32, 16><<<(NN + 15) / 16, 256, 0, stream>>>(msgb, perm, base, x1, root1, bias1, h1);
  k_stats<16><<<128, 256, 0, stream>>>(h1, ssum1, ssq1);
  k_bn<16, false><<<((NN * 16 / 4) + 255) / 256, 256, 0, stream>>>(h1, ssum1, ssq1, gam1, bet1, (float*)d_out);
}